// Round 15
// baseline (308.834 us; speedup 1.0000x reference)
//
#include <hip/hip_runtime.h>
#include <hip/hip_fp16.h>
#include <math.h>

#define N_NODES 50000
#define N_EDGES 800000
#define FEAT 128
#define EPS_W 1e-12f

// bucket = node >> 8 : 256 nodes per bucket, 196 buckets covers 50000
#define NB_BUCKET 196
#define NBLK_AB 256          // blocks for hist/scatter passes
#define CHUNK 3125           // edges per pass block (256*3125 = 800000)
#define SCAN_N (NB_BUCKET * NBLK_AB)   // 50176 = 49*1024 exactly
#define GEMM_BLOCKS 3125     // 50000 / 16

typedef unsigned long long u64;
typedef _Float16 f16x8 __attribute__((ext_vector_type(8)));
typedef float f32x4 __attribute__((ext_vector_type(4)));

// ---------- helpers ----------
__device__ __forceinline__ float selu_f(float x) {
  const float scale = 1.0507009873554805f;
  const float alpha = 1.6732632423543772f;
  return x > 0.f ? scale * x : scale * alpha * expm1f(x);
}

__device__ __forceinline__ float2 h2f2(unsigned int u) {
  __half2 h = *reinterpret_cast<__half2*>(&u);
  return __half22float2(h);
}

__device__ __forceinline__ float inv_norm(float wdeg, float cnt) {
  return (1.0f / sqrtf(fmaxf(wdeg, EPS_W))) * (1.0f / sqrtf(fmaxf(cnt, 1.0f)));
}

// ---------- MFMA GEMM body: 16 rows of A(fp32) @ W(frag fp16) ----------------
// Output CG-MAJOR: buf[cg][row][32] fp16, cg = wid (cols wid*32..wid*32+31).
__device__ __forceinline__ void gemm16_mfma_body(
    const float* __restrict__ A, const __half* __restrict__ wh,
    __half* __restrict__ out, int row0, __half* aL /*16*136 LDS*/) {
  int t = threadIdx.x;
  for (int i = t; i < 16 * 32; i += 256) {       // i = float4 index
    int r = i >> 5, c4 = i & 31;
    float4 v = ((const float4*)(A + (size_t)(row0 + r) * 128))[c4];
    __half2* hp = (__half2*)&aL[r * 136 + c4 * 4];
    hp[0] = __floats2half2_rn(v.x, v.y);
    hp[1] = __floats2half2_rn(v.z, v.w);
  }
  __syncthreads();
  int wid = t >> 6, lane = t & 63;
  f32x4 acc0 = {0.f, 0.f, 0.f, 0.f}, acc1 = {0.f, 0.f, 0.f, 0.f};
  const f16x8* w8 = (const f16x8*)wh;
#pragma unroll
  for (int ks = 0; ks < 4; ++ks) {
    f16x8 af = *(const f16x8*)&aL[(lane & 15) * 136 + ks * 32 + (lane >> 4) * 8];
    f16x8 bf0 = w8[((wid * 2 + 0) * 4 + ks) * 64 + lane];
    f16x8 bf1 = w8[((wid * 2 + 1) * 4 + ks) * 64 + lane];
    acc0 = __builtin_amdgcn_mfma_f32_16x16x32_f16(af, bf0, acc0, 0, 0, 0);
    acc1 = __builtin_amdgcn_mfma_f32_16x16x32_f16(af, bf1, acc1, 0, 0, 0);
  }
  // C/D: col = lane&15 (+16*tile), row = (lane>>4)*4 + reg; cg = wid
  int crow = row0 + (lane >> 4) * 4;
  int cc = lane & 15;
#pragma unroll
  for (int r = 0; r < 4; ++r) {
    size_t base = ((size_t)wid * N_NODES + crow + r) * 32;
    out[base + cc]      = __float2half_rn(acc0[r]);
    out[base + cc + 16] = __float2half_rn(acc1[r]);
  }
}

// ---------- 1. per-block bucket histograms + W1/W2 fragment transforms -------
__global__ __launch_bounds__(256) void pass_hist(
    const int* __restrict__ src, const int* __restrict__ dst,
    int* __restrict__ dMat, int* __restrict__ sMat,
    const float* __restrict__ W1, const float* __restrict__ W2,
    __half* __restrict__ w1h, __half* __restrict__ w2h) {
  if (blockIdx.x >= NBLK_AB) {
    const float* Wsrc = (blockIdx.x == NBLK_AB) ? W1 : W2;
    __half* wdst = (blockIdx.x == NBLK_AB) ? w1h : w2h;
    for (int f = threadIdx.x; f < 2048; f += 256) {
      int l = f & 63, ks = (f >> 6) & 3, nt = f >> 8;
      int kbase = ks * 32 + (l >> 4) * 8;
      int col = nt * 16 + (l & 15);
      __align__(16) __half tmp[8];
#pragma unroll
      for (int j = 0; j < 8; ++j)
        tmp[j] = __float2half_rn(Wsrc[(kbase + j) * 128 + col]);
      *(uint4*)&wdst[f * 8] = *(const uint4*)tmp;
    }
    return;
  }
  __shared__ int hd[NB_BUCKET], hs[NB_BUCKET];
  for (int i = threadIdx.x; i < NB_BUCKET; i += 256) { hd[i] = 0; hs[i] = 0; }
  __syncthreads();
  int blk = blockIdx.x;
  int base = blk * CHUNK;
  for (int i = threadIdx.x; i < CHUNK; i += 256) {
    int e = base + i;
    atomicAdd(&hd[dst[e] >> 8], 1);
    atomicAdd(&hs[src[e] >> 8], 1);
  }
  __syncthreads();
  for (int i = threadIdx.x; i < NB_BUCKET; i += 256) {
    dMat[i * NBLK_AB + blk] = hd[i];
    sMat[i * NBLK_AB + blk] = hs[i];
  }
}

// ---------- 2. in-place exclusive scan of the two 50176-entry matrices --------
__global__ __launch_bounds__(1024) void scan_mat(int* __restrict__ dMat,
                                                 int* __restrict__ sMat) {
  int* m = (blockIdx.x == 0) ? dMat : sMat;
  __shared__ int sh[1024];
  int t = threadIdx.x;
  const int CH = 49;  // 1024*49 = 50176 == SCAN_N exactly
  int s0 = t * CH;
  int v[CH];
  int sum = 0;
#pragma unroll
  for (int j = 0; j < CH; ++j) {
    v[j] = m[s0 + j];
    sum += v[j];
  }
  sh[t] = sum;
  __syncthreads();
  for (int off = 1; off < 1024; off <<= 1) {
    int x = (t >= off) ? sh[t - off] : 0;
    __syncthreads();
    sh[t] += x;
    __syncthreads();
  }
  int excl = sh[t] - sum;
#pragma unroll
  for (int j = 0; j < CH; ++j) {
    m[s0 + j] = excl;
    excl += v[j];
  }
}

// ---------- 3. FUSED: exact-slot bucket scatter (no global atomics) || GEMM ---
__global__ __launch_bounds__(256) void fused_scatter_gemm(
    const int* __restrict__ src, const int* __restrict__ dst,
    const float* __restrict__ ew,
    const int* __restrict__ dMat, const int* __restrict__ sMat,
    int2* __restrict__ dRec, unsigned* __restrict__ sRec,
    const float* __restrict__ x, const __half* __restrict__ w1h,
    __half* __restrict__ bufG) {
  __shared__ __half aL[16 * 136];
  __shared__ int curD[NB_BUCKET], curS[NB_BUCKET];
  if (blockIdx.x >= NBLK_AB) {
    gemm16_mfma_body(x, w1h, bufG, (blockIdx.x - NBLK_AB) * 16, aL);
    return;
  }
  int blk = blockIdx.x;
  for (int i = threadIdx.x; i < NB_BUCKET; i += 256) {
    curD[i] = dMat[i * NBLK_AB + blk];
    curS[i] = sMat[i * NBLK_AB + blk];
  }
  __syncthreads();
  int base = blk * CHUNK;
  for (int i = threadIdx.x; i < CHUNK; i += 256) {
    int e = base + i;
    int s = src[e], d = dst[e];
    float w = ew[e];
    int pd = atomicAdd(&curD[d >> 8], 1);           // LDS atomic
    int2 r; r.x = (s << 8) | (d & 255); r.y = __float_as_int(w);
    dRec[pd] = r;
    int ps = atomicAdd(&curS[s >> 8], 1);           // LDS atomic
    unsigned q = (unsigned)__float2uint_rn(w * 8388608.0f) & 0xFFFFFFu;  // Q23
    sRec[ps] = ((unsigned)(s & 255) << 24) | q;
  }
}

// ---------- 4. node stats (FUSED): src-reduce -> inv_out || dst-hist ->
// rowptr + inv_in.  392 blocks x 512 threads.
__global__ __launch_bounds__(512) void node_stats(
    const unsigned* __restrict__ sRec, const int* __restrict__ sMat,
    const int2* __restrict__ dRec, const int* __restrict__ dMat,
    float* __restrict__ inv_out, float* __restrict__ inv_in,
    int* __restrict__ rowptr) {
  __shared__ float wdeg[256];
  __shared__ int cnt[256];
  __shared__ int excl[256];
  int t = threadIdx.x;
  if (t < 256) { wdeg[t] = 0.f; cnt[t] = 0; }
  __syncthreads();
  if (blockIdx.x < NB_BUCKET) {
    int b = blockIdx.x;
    int s0 = sMat[b * NBLK_AB];
    int s1 = (b == NB_BUCKET - 1) ? N_EDGES : sMat[(b + 1) * NBLK_AB];
    for (int i = s0 + t; i < s1; i += 512) {
      unsigned r = sRec[i];
      atomicAdd(&wdeg[r >> 24], (float)(r & 0xFFFFFFu) * (1.0f / 8388608.0f));
      atomicAdd(&cnt[r >> 24], 1);
    }
    __syncthreads();
    if (t < 256) {
      int nodeg = b * 256 + t;
      if (nodeg < N_NODES)
        inv_out[nodeg] = inv_norm(wdeg[t], (float)cnt[t]);
    }
  } else {
    int b = blockIdx.x - NB_BUCKET;
    int s0 = dMat[b * NBLK_AB];
    int s1 = (b == NB_BUCKET - 1) ? N_EDGES : dMat[(b + 1) * NBLK_AB];
    for (int i = s0 + t; i < s1; i += 512) {
      int2 r = dRec[i];
      atomicAdd(&cnt[r.x & 255], 1);
      atomicAdd(&wdeg[r.x & 255], __int_as_float(r.y));
    }
    __syncthreads();
    int myc = (t < 256) ? cnt[t] : 0;
    if (t < 256) excl[t] = myc;
    __syncthreads();
    for (int off = 1; off < 256; off <<= 1) {
      int x = (t >= off && t < 256) ? excl[t - off] : 0;
      __syncthreads();
      if (t < 256) excl[t] += x;
      __syncthreads();
    }
    if (t < 256) {
      int myexcl = excl[t] - myc;
      int nodeg = b * 256 + t;
      if (nodeg < N_NODES) {
        rowptr[nodeg] = s0 + myexcl;
        inv_in[nodeg] = inv_norm(wdeg[t], (float)cnt[t]);
      }
      if (b == NB_BUCKET - 1 && t == 0) rowptr[N_NODES] = N_EDGES;
    }
  }
}

// ---------- 5. placement: cursors from rowptr, write final CSR edges ---------
__global__ __launch_bounds__(512) void fill_edges(
    const int2* __restrict__ dRec, const int* __restrict__ dMat,
    const float* __restrict__ inv_out, const float* __restrict__ inv_in,
    const int* __restrict__ rowptr, int2* __restrict__ edges) {
  __shared__ int cur[256];
  __shared__ float invin[256];
  int b = blockIdx.x, t = threadIdx.x;
  if (t < 256) {
    int nodeg = b * 256 + t;
    cur[t] = (nodeg < N_NODES) ? rowptr[nodeg] : 0;
    invin[t] = (nodeg < N_NODES) ? inv_in[nodeg] : 0.f;
  }
  __syncthreads();
  int s0 = dMat[b * NBLK_AB];
  int s1 = (b == NB_BUCKET - 1) ? N_EDGES : dMat[(b + 1) * NBLK_AB];
  for (int i = s0 + t; i < s1; i += 512) {
    int2 r = dRec[i];
    int node = r.x & 255;
    int srcn = ((unsigned)r.x) >> 8;
    float c = __int_as_float(r.y) * inv_out[srcn] * invin[node];
    int pos = atomicAdd(&cur[node], 1);             // LDS atomic -> rank
    int2 rec; rec.x = srcn; rec.y = __float_as_int(c);
    edges[pos] = rec;
  }
}

// ---------- split-K cg gather: 32 lanes/row = 4 edge-subgroups x 8 col-lanes -
// Subgroup g handles edges beg+g, beg+g+4, ... ; lane loads a DENSE uint2 (8B)
// of the 64B cg slice. Partial sums reduced via shfl_xor(8,16) at the end.
// 2 rows/wave (low divergence), 8B loads, L2-resident slice: r11 shape + r14
// residency.
__device__ __forceinline__ float4 gather_cg_sk(
    const int* __restrict__ rowptr, const int2* __restrict__ edges,
    const uint2* __restrict__ xin2, int row, int g, int s) {
  int beg = rowptr[row], end = rowptr[row + 1];
  float4 acc = make_float4(0.f, 0.f, 0.f, 0.f);
  const u64* ep = (const u64*)edges;
  int e = beg + g;
  for (; e + 4 < end; e += 8) {          // 2-deep per subgroup (8 edges/row)
    u64 p0 = __builtin_nontemporal_load(ep + e);
    u64 p1 = __builtin_nontemporal_load(ep + e + 4);
    uint2 q0 = xin2[(size_t)(unsigned)(p0 & 0xffffffffu) * 8 + s];
    uint2 q1 = xin2[(size_t)(unsigned)(p1 & 0xffffffffu) * 8 + s];
    float c0 = __int_as_float((int)(p0 >> 32));
    float c1 = __int_as_float((int)(p1 >> 32));
    float2 l0 = h2f2(q0.x), h0 = h2f2(q0.y);
    float2 l1 = h2f2(q1.x), h1 = h2f2(q1.y);
    acc.x += c0 * l0.x + c1 * l1.x;
    acc.y += c0 * l0.y + c1 * l1.y;
    acc.z += c0 * h0.x + c1 * h1.x;
    acc.w += c0 * h0.y + c1 * h1.y;
  }
  for (; e < end; e += 4) {
    u64 p0 = __builtin_nontemporal_load(ep + e);
    uint2 q0 = xin2[(size_t)(unsigned)(p0 & 0xffffffffu) * 8 + s];
    float c0 = __int_as_float((int)(p0 >> 32));
    float2 l0 = h2f2(q0.x), h0 = h2f2(q0.y);
    acc.x += c0 * l0.x;
    acc.y += c0 * l0.y;
    acc.z += c0 * h0.x;
    acc.w += c0 * h0.y;
  }
  // reduce the 4 subgroup partials (lanes differ in bits 3..4)
#pragma unroll
  for (int off = 8; off <= 16; off <<= 1) {
    acc.x += __shfl_xor(acc.x, off);
    acc.y += __shfl_xor(acc.y, off);
    acc.z += __shfl_xor(acc.z, off);
    acc.w += __shfl_xor(acc.w, off);
  }
  return acc;
}

// ---------- 6a. layer-1 spmm (cg-split, cg-major, split-K): -> fp16 bufH -----
// cg = blockIdx&3 -> 3.2 MB dense slice per XCD (fits 4 MB L2). 8 rows/block.
__global__ __launch_bounds__(256) void spmm_cg_f16(
    const int* __restrict__ rowptr, const int2* __restrict__ edges,
    const uint2* __restrict__ bufG2, const float* __restrict__ bias,
    uint2* __restrict__ bufH2) {
  int cg = blockIdx.x & 3, rb = blockIdx.x >> 2;
  int t = threadIdx.x;
  int row = rb * 8 + (t >> 5);               // grid exact: 6250*8 = 50000
  int rl = t & 31, g = rl >> 3, s = rl & 7;
  const uint2* xin2 = bufG2 + (size_t)cg * N_NODES * 8;
  float4 a = gather_cg_sk(rowptr, edges, xin2, row, g, s);
  if (g == 0) {
    float4 b = ((const float4*)(bias + cg * 32))[s];
    __half2 h0 = __floats2half2_rn(selu_f(a.x + b.x), selu_f(a.y + b.y));
    __half2 h1 = __floats2half2_rn(selu_f(a.z + b.z), selu_f(a.w + b.w));
    uint2 o; o.x = *(unsigned*)&h0; o.y = *(unsigned*)&h1;
    bufH2[((size_t)cg * N_NODES + row) * 8 + s] = o;
  }
}

// ---------- 6b. MFMA @W2, IN PLACE on the cg-major fp16 buffer ---------------
// Stage 16 rows (all 4 cg slices) -> LDS, barrier, overwrite same rows.
__global__ __launch_bounds__(256) void gemm_w2_inplace(
    const __half* __restrict__ wh, __half* buf) {
  __shared__ __half aL[16 * 136];
  int t = threadIdx.x;
  int row0 = blockIdx.x * 16;
  const unsigned* bu = (const unsigned*)buf;
  for (int i = t; i < 16 * 64; i += 256) {     // i = uint index within row set
    int r = i >> 6, c2 = i & 63;               // c2: 64 uints = 128 halfs
    int cg = c2 >> 4, w16 = c2 & 15;
    *(unsigned*)&aL[r * 136 + c2 * 2] =
        bu[((size_t)cg * N_NODES + row0 + r) * 16 + w16];
  }
  __syncthreads();
  int wid = t >> 6, lane = t & 63;
  f32x4 acc0 = {0.f, 0.f, 0.f, 0.f}, acc1 = {0.f, 0.f, 0.f, 0.f};
  const f16x8* w8 = (const f16x8*)wh;
#pragma unroll
  for (int ks = 0; ks < 4; ++ks) {
    f16x8 af = *(const f16x8*)&aL[(lane & 15) * 136 + ks * 32 + (lane >> 4) * 8];
    f16x8 bf0 = w8[((wid * 2 + 0) * 4 + ks) * 64 + lane];
    f16x8 bf1 = w8[((wid * 2 + 1) * 4 + ks) * 64 + lane];
    acc0 = __builtin_amdgcn_mfma_f32_16x16x32_f16(af, bf0, acc0, 0, 0, 0);
    acc1 = __builtin_amdgcn_mfma_f32_16x16x32_f16(af, bf1, acc1, 0, 0, 0);
  }
  int crow = row0 + (lane >> 4) * 4;
  int cc = lane & 15;
#pragma unroll
  for (int r = 0; r < 4; ++r) {
    size_t base = ((size_t)wid * N_NODES + crow + r) * 32;
    buf[base + cc]      = __float2half_rn(acc0[r]);
    buf[base + cc + 16] = __float2half_rn(acc1[r]);
  }
}

// ---------- 6c. layer-2 spmm (cg-split, cg-major, split-K): -> fp32 out ------
__global__ __launch_bounds__(256) void spmm_cg_f32(
    const int* __restrict__ rowptr, const int2* __restrict__ edges,
    const uint2* __restrict__ bufB2, const float* __restrict__ bias,
    float* __restrict__ out) {
  int cg = blockIdx.x & 3, rb = blockIdx.x >> 2;
  int t = threadIdx.x;
  int row = rb * 8 + (t >> 5);
  int rl = t & 31, g = rl >> 3, s = rl & 7;
  const uint2* xin2 = bufB2 + (size_t)cg * N_NODES * 8;
  float4 a = gather_cg_sk(rowptr, edges, xin2, row, g, s);
  if (g == 0) {
    float4 b = ((const float4*)(bias + cg * 32))[s];
    f32x4 r;
    r[0] = selu_f(a.x + b.x);
    r[1] = selu_f(a.y + b.y);
    r[2] = selu_f(a.z + b.z);
    r[3] = selu_f(a.w + b.w);
    // out is never re-read: nontemporal, row-major [N][128] fp32
    __builtin_nontemporal_store(
        r, (f32x4*)(out + (size_t)row * 128 + cg * 32 + s * 4));
  }
}

extern "C" void kernel_launch(void* const* d_in, const int* in_sizes, int n_in,
                              void* d_out, int out_size, void* d_ws, size_t ws_size,
                              hipStream_t stream) {
  const float* x   = (const float*)d_in[0];
  const int*   src = (const int*)d_in[1];
  const int*   dst = (const int*)d_in[2];
  const float* ew  = (const float*)d_in[3];
  const float* W1  = (const float*)d_in[4];
  const float* b1  = (const float*)d_in[5];
  const float* W2  = (const float*)d_in[6];
  const float* b2  = (const float*)d_in[7];
  float* out = (float*)d_out;

  // workspace layout (temporal aliasing: edges over sRec; bufH over dRec)
  char* ws = (char*)d_ws;
  int*   dMat    = (int*)(ws + 0);              //   200,704 B (196*256*4)
  int*   sMat    = (int*)(ws + 200704);         //   200,704 B -> 401,408
  float* inv_out = (float*)(ws + 401408);       //   200,000 B -> 601,408
  float* inv_in  = (float*)(ws + 601408);       //   200,000 B -> 801,408
  int*   rowptr  = (int*)(ws + 801408);         //   200,004 B -> 1,001,412
  __half* w1h    = (__half*)(ws + 1001424);     //    32,768 B -> 1,034,192 (16B)
  __half* w2h    = (__half*)(ws + 1034192);     //    32,768 B -> 1,066,960
  // union region A: sRec (3.2 MB, dead after node_stats) / edges (6.4 MB)
  unsigned* sRec = (unsigned*)(ws + 1066960);
  int2*  edges   = (int2*)(ws + 1066960);       // -> 7,466,960
  __half* bufG   = (__half*)(ws + 7466960);     // 12.8 MB cg-major -> 20,266,960
  // union region B: dRec (6.4 MB, dead before spmm_cg_f16 writes bufH);
  // bufH == bufB (gemm_w2_inplace transforms in place), cg-major
  int2*  dRec    = (int2*)(ws + 20266960);
  __half* bufH   = (__half*)(ws + 20266960);    // 12.8 MB -> 33,066,960

  // 1. bucket histograms (src & dst) + W1/W2 fragment transforms
  pass_hist<<<NBLK_AB + 2, 256, 0, stream>>>(src, dst, dMat, sMat,
                                             W1, W2, w1h, w2h);
  // 2. exclusive scan of both count matrices
  scan_mat<<<2, 1024, 0, stream>>>(dMat, sMat);
  // 3. exact-slot scatter || bufG = fp16(x @ W1), MFMA, cg-major
  fused_scatter_gemm<<<NBLK_AB + GEMM_BLOCKS, 256, 0, stream>>>(
      src, dst, ew, dMat, sMat, dRec, sRec, x, w1h, bufG);
  // 4. node stats: inv_out || rowptr + inv_in (fused, 512-thread)
  node_stats<<<2 * NB_BUCKET, 512, 0, stream>>>(sRec, sMat, dRec, dMat,
                                                inv_out, inv_in, rowptr);
  // 5. placement -> final CSR edges (src, c)
  fill_edges<<<NB_BUCKET, 512, 0, stream>>>(dRec, dMat, inv_out, inv_in,
                                            rowptr, edges);

  const int CG_BLOCKS = (N_NODES / 8) * 4;     // 25000: 6250 row-tiles x 4 cgs

  // 6a. layer-1 spmm, cg-split split-K: bufH = fp16( selu(A_hat·bufG + b1) )
  spmm_cg_f16<<<CG_BLOCKS, 256, 0, stream>>>(
      rowptr, edges, (const uint2*)bufG, b1, (uint2*)bufH);
  // 6b. bufB = bufH @ W2 (MFMA, in place, cg-major)
  gemm_w2_inplace<<<GEMM_BLOCKS, 256, 0, stream>>>(w2h, bufH);
  // 6c. layer-2 spmm, cg-split split-K: out = selu(A_hat·bufB + b2)
  spmm_cg_f32<<<CG_BLOCKS, 256, 0, stream>>>(
      rowptr, edges, (const uint2*)bufH, b2, out);
}

// Round 16
// 243.432 us; speedup vs baseline: 1.2687x; 1.2687x over previous
//
#include <hip/hip_runtime.h>
#include <hip/hip_fp16.h>
#include <math.h>

#define N_NODES 50000
#define N_EDGES 800000
#define FEAT 128
#define EPS_W 1e-12f

// bucket = node >> 8 : 256 nodes per bucket, 196 buckets covers 50000
#define NB_BUCKET 196
#define NBLK_AB 256          // blocks for hist/scatter passes
#define CHUNK 3125           // edges per pass block (256*3125 = 800000)
#define SCAN_N (NB_BUCKET * NBLK_AB)   // 50176 = 49*1024 exactly
#define GEMM_BLOCKS 3125     // 50000 / 16

typedef unsigned long long u64;
typedef _Float16 f16x8 __attribute__((ext_vector_type(8)));
typedef float f32x4 __attribute__((ext_vector_type(4)));

// ---------- helpers ----------
__device__ __forceinline__ float selu_f(float x) {
  const float scale = 1.0507009873554805f;
  const float alpha = 1.6732632423543772f;
  return x > 0.f ? scale * x : scale * alpha * expm1f(x);
}

__device__ __forceinline__ float2 h2f2(unsigned int u) {
  __half2 h = *reinterpret_cast<__half2*>(&u);
  return __half22float2(h);
}

__device__ __forceinline__ float inv_norm(float wdeg, float cnt) {
  return (1.0f / sqrtf(fmaxf(wdeg, EPS_W))) * (1.0f / sqrtf(fmaxf(cnt, 1.0f)));
}

// ---------- MFMA GEMM body: 16 rows of A(fp32) @ W(frag fp16) -> fp16 out ----
__device__ __forceinline__ void gemm16_mfma_body(
    const float* __restrict__ A, const __half* __restrict__ wh,
    __half* __restrict__ out, int row0, __half* aL /*16*136 LDS*/) {
  int t = threadIdx.x;
  for (int i = t; i < 16 * 32; i += 256) {       // i = float4 index
    int r = i >> 5, c4 = i & 31;
    float4 v = ((const float4*)(A + (size_t)(row0 + r) * 128))[c4];
    __half2* hp = (__half2*)&aL[r * 136 + c4 * 4];
    hp[0] = __floats2half2_rn(v.x, v.y);
    hp[1] = __floats2half2_rn(v.z, v.w);
  }
  __syncthreads();
  int wid = t >> 6, lane = t & 63;
  f32x4 acc0 = {0.f, 0.f, 0.f, 0.f}, acc1 = {0.f, 0.f, 0.f, 0.f};
  const f16x8* w8 = (const f16x8*)wh;
#pragma unroll
  for (int ks = 0; ks < 4; ++ks) {
    f16x8 af = *(const f16x8*)&aL[(lane & 15) * 136 + ks * 32 + (lane >> 4) * 8];
    f16x8 bf0 = w8[((wid * 2 + 0) * 4 + ks) * 64 + lane];
    f16x8 bf1 = w8[((wid * 2 + 1) * 4 + ks) * 64 + lane];
    acc0 = __builtin_amdgcn_mfma_f32_16x16x32_f16(af, bf0, acc0, 0, 0, 0);
    acc1 = __builtin_amdgcn_mfma_f32_16x16x32_f16(af, bf1, acc1, 0, 0, 0);
  }
  // C/D: col = lane&15 (+16*tile), row = (lane>>4)*4 + reg
  int crow = row0 + (lane >> 4) * 4;
  int c0 = wid * 32 + (lane & 15);
#pragma unroll
  for (int r = 0; r < 4; ++r) {
    out[(size_t)(crow + r) * 128 + c0]      = __float2half_rn(acc0[r]);
    out[(size_t)(crow + r) * 128 + c0 + 16] = __float2half_rn(acc1[r]);
  }
}

// ---------- 1. per-block bucket histograms + W1/W2 fragment transforms -------
__global__ __launch_bounds__(256) void pass_hist(
    const int* __restrict__ src, const int* __restrict__ dst,
    int* __restrict__ dMat, int* __restrict__ sMat,
    const float* __restrict__ W1, const float* __restrict__ W2,
    __half* __restrict__ w1h, __half* __restrict__ w2h) {
  if (blockIdx.x >= NBLK_AB) {
    const float* Wsrc = (blockIdx.x == NBLK_AB) ? W1 : W2;
    __half* wdst = (blockIdx.x == NBLK_AB) ? w1h : w2h;
    for (int f = threadIdx.x; f < 2048; f += 256) {
      int l = f & 63, ks = (f >> 6) & 3, nt = f >> 8;
      int kbase = ks * 32 + (l >> 4) * 8;
      int col = nt * 16 + (l & 15);
      __align__(16) __half tmp[8];
#pragma unroll
      for (int j = 0; j < 8; ++j)
        tmp[j] = __float2half_rn(Wsrc[(kbase + j) * 128 + col]);
      *(uint4*)&wdst[f * 8] = *(const uint4*)tmp;
    }
    return;
  }
  __shared__ int hd[NB_BUCKET], hs[NB_BUCKET];
  for (int i = threadIdx.x; i < NB_BUCKET; i += 256) { hd[i] = 0; hs[i] = 0; }
  __syncthreads();
  int blk = blockIdx.x;
  int base = blk * CHUNK;
  for (int i = threadIdx.x; i < CHUNK; i += 256) {
    int e = base + i;
    atomicAdd(&hd[dst[e] >> 8], 1);
    atomicAdd(&hs[src[e] >> 8], 1);
  }
  __syncthreads();
  for (int i = threadIdx.x; i < NB_BUCKET; i += 256) {
    dMat[i * NBLK_AB + blk] = hd[i];
    sMat[i * NBLK_AB + blk] = hs[i];
  }
}

// ---------- 2. in-place exclusive scan of the two 50176-entry matrices --------
__global__ __launch_bounds__(1024) void scan_mat(int* __restrict__ dMat,
                                                 int* __restrict__ sMat) {
  int* m = (blockIdx.x == 0) ? dMat : sMat;
  __shared__ int sh[1024];
  int t = threadIdx.x;
  const int CH = 49;  // 1024*49 = 50176 == SCAN_N exactly
  int s0 = t * CH;
  int v[CH];
  int sum = 0;
#pragma unroll
  for (int j = 0; j < CH; ++j) {
    v[j] = m[s0 + j];
    sum += v[j];
  }
  sh[t] = sum;
  __syncthreads();
  for (int off = 1; off < 1024; off <<= 1) {
    int x = (t >= off) ? sh[t - off] : 0;
    __syncthreads();
    sh[t] += x;
    __syncthreads();
  }
  int excl = sh[t] - sum;
#pragma unroll
  for (int j = 0; j < CH; ++j) {
    m[s0 + j] = excl;
    excl += v[j];
  }
}

// ---------- 3. FUSED: exact-slot bucket scatter (no global atomics) || GEMM ---
__global__ __launch_bounds__(256) void fused_scatter_gemm(
    const int* __restrict__ src, const int* __restrict__ dst,
    const float* __restrict__ ew,
    const int* __restrict__ dMat, const int* __restrict__ sMat,
    int2* __restrict__ dRec, unsigned* __restrict__ sRec,
    const float* __restrict__ x, const __half* __restrict__ w1h,
    __half* __restrict__ bufG) {
  __shared__ __half aL[16 * 136];
  __shared__ int curD[NB_BUCKET], curS[NB_BUCKET];
  if (blockIdx.x >= NBLK_AB) {
    gemm16_mfma_body(x, w1h, bufG, (blockIdx.x - NBLK_AB) * 16, aL);
    return;
  }
  int blk = blockIdx.x;
  for (int i = threadIdx.x; i < NB_BUCKET; i += 256) {
    curD[i] = dMat[i * NBLK_AB + blk];
    curS[i] = sMat[i * NBLK_AB + blk];
  }
  __syncthreads();
  int base = blk * CHUNK;
  for (int i = threadIdx.x; i < CHUNK; i += 256) {
    int e = base + i;
    int s = src[e], d = dst[e];
    float w = ew[e];
    int pd = atomicAdd(&curD[d >> 8], 1);           // LDS atomic
    int2 r; r.x = (s << 8) | (d & 255); r.y = __float_as_int(w);
    dRec[pd] = r;
    int ps = atomicAdd(&curS[s >> 8], 1);           // LDS atomic
    unsigned q = (unsigned)__float2uint_rn(w * 8388608.0f) & 0xFFFFFFu;  // Q23
    sRec[ps] = ((unsigned)(s & 255) << 24) | q;
  }
}

// ---------- 4. node stats (FUSED): src-reduce -> inv_out || dst-hist ->
// rowptr + inv_in.  392 blocks x 512 threads.
__global__ __launch_bounds__(512) void node_stats(
    const unsigned* __restrict__ sRec, const int* __restrict__ sMat,
    const int2* __restrict__ dRec, const int* __restrict__ dMat,
    float* __restrict__ inv_out, float* __restrict__ inv_in,
    int* __restrict__ rowptr) {
  __shared__ float wdeg[256];
  __shared__ int cnt[256];
  __shared__ int excl[256];
  int t = threadIdx.x;
  if (t < 256) { wdeg[t] = 0.f; cnt[t] = 0; }
  __syncthreads();
  if (blockIdx.x < NB_BUCKET) {
    int b = blockIdx.x;
    int s0 = sMat[b * NBLK_AB];
    int s1 = (b == NB_BUCKET - 1) ? N_EDGES : sMat[(b + 1) * NBLK_AB];
    for (int i = s0 + t; i < s1; i += 512) {
      unsigned r = sRec[i];
      atomicAdd(&wdeg[r >> 24], (float)(r & 0xFFFFFFu) * (1.0f / 8388608.0f));
      atomicAdd(&cnt[r >> 24], 1);
    }
    __syncthreads();
    if (t < 256) {
      int nodeg = b * 256 + t;
      if (nodeg < N_NODES)
        inv_out[nodeg] = inv_norm(wdeg[t], (float)cnt[t]);
    }
  } else {
    int b = blockIdx.x - NB_BUCKET;
    int s0 = dMat[b * NBLK_AB];
    int s1 = (b == NB_BUCKET - 1) ? N_EDGES : dMat[(b + 1) * NBLK_AB];
    for (int i = s0 + t; i < s1; i += 512) {
      int2 r = dRec[i];
      atomicAdd(&cnt[r.x & 255], 1);
      atomicAdd(&wdeg[r.x & 255], __int_as_float(r.y));
    }
    __syncthreads();
    int myc = (t < 256) ? cnt[t] : 0;
    if (t < 256) excl[t] = myc;
    __syncthreads();
    for (int off = 1; off < 256; off <<= 1) {
      int x = (t >= off && t < 256) ? excl[t - off] : 0;
      __syncthreads();
      if (t < 256) excl[t] += x;
      __syncthreads();
    }
    if (t < 256) {
      int myexcl = excl[t] - myc;
      int nodeg = b * 256 + t;
      if (nodeg < N_NODES) {
        rowptr[nodeg] = s0 + myexcl;
        inv_in[nodeg] = inv_norm(wdeg[t], (float)cnt[t]);
      }
      if (b == NB_BUCKET - 1 && t == 0) rowptr[N_NODES] = N_EDGES;
    }
  }
}

// ---------- 5. placement: cursors from rowptr, write final CSR edges ---------
__global__ __launch_bounds__(512) void fill_edges(
    const int2* __restrict__ dRec, const int* __restrict__ dMat,
    const float* __restrict__ inv_out, const float* __restrict__ inv_in,
    const int* __restrict__ rowptr, int2* __restrict__ edges) {
  __shared__ int cur[256];
  __shared__ float invin[256];
  int b = blockIdx.x, t = threadIdx.x;
  if (t < 256) {
    int nodeg = b * 256 + t;
    cur[t] = (nodeg < N_NODES) ? rowptr[nodeg] : 0;
    invin[t] = (nodeg < N_NODES) ? inv_in[nodeg] : 0.f;
  }
  __syncthreads();
  int s0 = dMat[b * NBLK_AB];
  int s1 = (b == NB_BUCKET - 1) ? N_EDGES : dMat[(b + 1) * NBLK_AB];
  for (int i = s0 + t; i < s1; i += 512) {
    int2 r = dRec[i];
    int node = r.x & 255;
    int srcn = ((unsigned)r.x) >> 8;
    float c = __int_as_float(r.y) * inv_out[srcn] * invin[node];
    int pos = atomicAdd(&cur[node], 1);             // LDS atomic -> rank
    int2 rec; rec.x = srcn; rec.y = __float_as_int(c);
    edges[pos] = rec;
  }
}

// ---------- half-wave gather: 32 lanes cover a 128-wide fp16 row ----------
__device__ __forceinline__ float4 gather_row_half(
    const int* __restrict__ rowptr, const int2* __restrict__ edges,
    const uint2* __restrict__ xh /* row stride 32 */, int row, int sub) {
  int beg = rowptr[row], end = rowptr[row + 1];
  float4 acc = make_float4(0.f, 0.f, 0.f, 0.f);
  int e = beg;
  for (; e + 7 < end; e += 8) {
    int2 p0 = edges[e + 0], p1 = edges[e + 1], p2 = edges[e + 2], p3 = edges[e + 3];
    int2 p4 = edges[e + 4], p5 = edges[e + 5], p6 = edges[e + 6], p7 = edges[e + 7];
    uint2 q0 = xh[(size_t)p0.x * 32 + sub];
    uint2 q1 = xh[(size_t)p1.x * 32 + sub];
    uint2 q2 = xh[(size_t)p2.x * 32 + sub];
    uint2 q3 = xh[(size_t)p3.x * 32 + sub];
    uint2 q4 = xh[(size_t)p4.x * 32 + sub];
    uint2 q5 = xh[(size_t)p5.x * 32 + sub];
    uint2 q6 = xh[(size_t)p6.x * 32 + sub];
    uint2 q7 = xh[(size_t)p7.x * 32 + sub];
#define ACC_EDGE(P, Q)                                              \
    {                                                               \
      float cc = __int_as_float(P.y);                               \
      float2 lo = h2f2(Q.x);                                        \
      float2 hi = h2f2(Q.y);                                        \
      acc.x += cc * lo.x; acc.y += cc * lo.y;                       \
      acc.z += cc * hi.x; acc.w += cc * hi.y;                       \
    }
    ACC_EDGE(p0, q0) ACC_EDGE(p1, q1) ACC_EDGE(p2, q2) ACC_EDGE(p3, q3)
    ACC_EDGE(p4, q4) ACC_EDGE(p5, q5) ACC_EDGE(p6, q6) ACC_EDGE(p7, q7)
  }
  for (; e < end; ++e) {
    int2 p0 = edges[e];
    uint2 q0 = xh[(size_t)p0.x * 32 + sub];
    ACC_EDGE(p0, q0)
  }
#undef ACC_EDGE
  return acc;
}

// ---------- 6a. layer-1: spmm + bias + selu + MFMA @W2 -> fp16 bufB ----------
// 8 rows/block (gather TLP preserved). MFMA M-dim zero-padded to 16.
__global__ __launch_bounds__(256) void spmm_selu_gemm(
    const int* __restrict__ rowptr, const int2* __restrict__ edges,
    const uint2* __restrict__ g, const float* __restrict__ bias,
    const __half* __restrict__ w2h, __half* __restrict__ out) {
  __shared__ __half hL[16 * 136];
  int wid = threadIdx.x >> 6, lane = threadIdx.x & 63;
  int half_ = lane >> 5, sub = lane & 31;
  // zero-pad rows 8..15 (MFMA reads them; their C rows are discarded)
  for (int i = threadIdx.x; i < 8 * 136; i += 256)
    hL[8 * 136 + i] = __float2half_rn(0.f);
  int lrow = wid * 2 + half_;                // 0..7 within block
  int row = blockIdx.x * 8 + lrow;           // grid exact: row < n
  float4 a = gather_row_half(rowptr, edges, g, row, sub);
  float4 b = ((const float4*)bias)[sub];
  __half2* hp = (__half2*)&hL[lrow * 136 + sub * 4];
  hp[0] = __floats2half2_rn(selu_f(a.x + b.x), selu_f(a.y + b.y));
  hp[1] = __floats2half2_rn(selu_f(a.z + b.z), selu_f(a.w + b.w));
  __syncthreads();
  // C[16x128] = hL @ W2 ; wave w owns col-tiles 2w, 2w+1
  f32x4 acc0 = {0.f, 0.f, 0.f, 0.f}, acc1 = {0.f, 0.f, 0.f, 0.f};
  const f16x8* w8 = (const f16x8*)w2h;
#pragma unroll
  for (int ks = 0; ks < 4; ++ks) {
    f16x8 af = *(const f16x8*)&hL[(lane & 15) * 136 + ks * 32 + (lane >> 4) * 8];
    f16x8 bf0 = w8[((wid * 2 + 0) * 4 + ks) * 64 + lane];
    f16x8 bf1 = w8[((wid * 2 + 1) * 4 + ks) * 64 + lane];
    acc0 = __builtin_amdgcn_mfma_f32_16x16x32_f16(af, bf0, acc0, 0, 0, 0);
    acc1 = __builtin_amdgcn_mfma_f32_16x16x32_f16(af, bf1, acc1, 0, 0, 0);
  }
  // C/D layout: col = lane&15 (+16*tile), row = (lane>>4)*4 + reg; keep rows 0..7
  int hi = lane >> 4;
  if (hi < 2) {
    int crow = blockIdx.x * 8 + hi * 4;
    int c0 = wid * 32 + (lane & 15);
#pragma unroll
    for (int r = 0; r < 4; ++r) {
      out[(size_t)(crow + r) * 128 + c0]      = __float2half_rn(acc0[r]);
      out[(size_t)(crow + r) * 128 + c0 + 16] = __float2half_rn(acc1[r]);
    }
  }
}

// ---------- 6b. layer-2: spmm(fp16 bufB) + bias + selu -> fp32 output ----------
__global__ __launch_bounds__(256) void spmm_ep(
    const int* __restrict__ rowptr, const int2* __restrict__ edges,
    const uint2* __restrict__ xh, const float* __restrict__ bias,
    float* __restrict__ out, int n) {
  int wid = threadIdx.x >> 6, lane = threadIdx.x & 63;
  int half = lane >> 5, sub = lane & 31;
  int row = blockIdx.x * 8 + wid * 2 + half;   // grid exact
  float4 a = gather_row_half(rowptr, edges, xh, row, sub);
  float4 b = ((const float4*)bias)[sub];
  float4 r;
  r.x = selu_f(a.x + b.x);
  r.y = selu_f(a.y + b.y);
  r.z = selu_f(a.z + b.z);
  r.w = selu_f(a.w + b.w);
  ((float4*)out)[(size_t)row * 32 + sub] = r;
}

extern "C" void kernel_launch(void* const* d_in, const int* in_sizes, int n_in,
                              void* d_out, int out_size, void* d_ws, size_t ws_size,
                              hipStream_t stream) {
  const float* x   = (const float*)d_in[0];
  const int*   src = (const int*)d_in[1];
  const int*   dst = (const int*)d_in[2];
  const float* ew  = (const float*)d_in[3];
  const float* W1  = (const float*)d_in[4];
  const float* b1  = (const float*)d_in[5];
  const float* W2  = (const float*)d_in[6];
  const float* b2  = (const float*)d_in[7];
  float* out = (float*)d_out;

  // workspace layout (temporal aliasing: edges over sRec; dRec over bufB)
  char* ws = (char*)d_ws;
  int*   dMat    = (int*)(ws + 0);              //   200,704 B (196*256*4)
  int*   sMat    = (int*)(ws + 200704);         //   200,704 B -> 401,408
  float* inv_out = (float*)(ws + 401408);       //   200,000 B -> 601,408
  float* inv_in  = (float*)(ws + 601408);       //   200,000 B -> 801,408
  int*   rowptr  = (int*)(ws + 801408);         //   200,004 B -> 1,001,412
  __half* w1h    = (__half*)(ws + 1001424);     //    32,768 B -> 1,034,192 (16B)
  __half* w2h    = (__half*)(ws + 1034192);     //    32,768 B -> 1,066,960
  // union region A: sRec (3.2 MB, dead after node_stats) / edges (6.4 MB)
  unsigned* sRec = (unsigned*)(ws + 1066960);
  int2*  edges   = (int2*)(ws + 1066960);       // -> 7,466,960
  __half* bufG   = (__half*)(ws + 7466960);     // 12.8 MB -> 20,266,960
  // union region B: dRec (6.4 MB, dead before spmm_selu_gemm writes bufB)
  int2*  dRec    = (int2*)(ws + 20266960);
  __half* bufB   = (__half*)(ws + 20266960);    // 12.8 MB -> 33,066,960

  // 1. bucket histograms (src & dst) + W1/W2 fragment transforms
  pass_hist<<<NBLK_AB + 2, 256, 0, stream>>>(src, dst, dMat, sMat,
                                             W1, W2, w1h, w2h);
  // 2. exclusive scan of both count matrices
  scan_mat<<<2, 1024, 0, stream>>>(dMat, sMat);
  // 3. exact-slot scatter into bucket regions || bufG = fp16(x @ W1) via MFMA
  fused_scatter_gemm<<<NBLK_AB + GEMM_BLOCKS, 256, 0, stream>>>(
      src, dst, ew, dMat, sMat, dRec, sRec, x, w1h, bufG);
  // 4. node stats: inv_out || rowptr + inv_in (fused, 512-thread)
  node_stats<<<2 * NB_BUCKET, 512, 0, stream>>>(sRec, sMat, dRec, dMat,
                                                inv_out, inv_in, rowptr);
  // 5. placement -> final CSR edges (src, c)
  fill_edges<<<NB_BUCKET, 512, 0, stream>>>(dRec, dMat, inv_out, inv_in,
                                            rowptr, edges);

  const int RB8 = N_NODES / 8;                 // 6250 (8 rows / block, exact)

  // layer 1 + layer-2 GEMM: bufB = fp16( selu(A_hat·(x@W1) + b1) ) @ W2 (MFMA)
  spmm_selu_gemm<<<RB8, 256, 0, stream>>>(
      rowptr, edges, (const uint2*)bufG, b1, w2h, bufB);
  // layer 2: out = selu(A_hat·bufB + b2)
  spmm_ep<<<RB8, 256, 0, stream>>>(rowptr, edges, (const uint2*)bufB, b2,
                                   out, N_NODES);
}